// Round 6
// baseline (677.930 us; speedup 1.0000x reference)
//
#include <hip/hip_runtime.h>
#include <stdint.h>

#define T_DIM 1024
#define B_DIM 64
#define I_DIM 512
#define H_DIM 512
#define M_DIM (T_DIM*B_DIM)          // 65536 rows for both GEMMs
#define BH    (B_DIM*H_DIM)          // 32768
#define OUT_OFF ((size_t)M_DIM*H_DIM)  // 33554432 floats, then hiddens (B, 2H)

typedef __bf16 bf16x8 __attribute__((ext_vector_type(8)));
typedef float  f32x4  __attribute__((ext_vector_type(4)));

// ---------- helpers ----------
__device__ __forceinline__ void split1(float x, ushort& h, ushort& l) {
  uint32_t u  = __builtin_bit_cast(uint32_t, x);
  uint32_t hr = (u + 0x7FFFu + ((u >> 16) & 1u)) >> 16;
  float    hf = __builtin_bit_cast(float, hr << 16);
  float    lo = x - hf;
  uint32_t ul = __builtin_bit_cast(uint32_t, lo);
  uint32_t lr = (ul + 0x7FFFu + ((ul >> 16) & 1u)) >> 16;
  h = (ushort)hr; l = (ushort)lr;
}

#define GLOAD_LDS16(g, l)                                                     \
  __builtin_amdgcn_global_load_lds(                                           \
      (const __attribute__((address_space(1))) void*)(g),                     \
      (__attribute__((address_space(3))) void*)(l), 16, 0, 0)

#define VMCNT(n) asm volatile("s_waitcnt vmcnt(" #n ")" ::: "memory")

// ---------- split f32 -> (hi, lo) bf16 planes ----------
__global__ __launch_bounds__(256)
void split4_kernel(const float4* __restrict__ src, ushort4* __restrict__ hi,
                   ushort4* __restrict__ lo, int n4) {
  int i = blockIdx.x * blockDim.x + threadIdx.x;
  int stride = gridDim.x * blockDim.x;
  for (; i < n4; i += stride) {
    float4 v = src[i];
    ushort4 h4, l4;
    split1(v.x, h4.x, l4.x);
    split1(v.y, h4.y, l4.y);
    split1(v.z, h4.z, l4.z);
    split1(v.w, h4.w, l4.w);
    hi[i] = h4;
    lo[i] = l4;
  }
}

// ---------- term-grouped 256x256 GEMM, 8 physical k-tiles of BK=64 ----------
// Per group c: tiles (c,0)=Ahi*Whi, (c,1)=Ahi*Wlo, (c,2)=Alo*Whi.
// A-frags (16x bf16x8) persist across (c,0)->(c,1): (c,1) has NO A reads/stages.
// (c,2) reuses (c,0)'s B-slot (Whi): NO B stage for e=2.
// LDS slots As/Bs[2 buf][2 khalf][8192] (16KB), st swizzle byte^=((byte>>9)&1)<<5
// on stage-source AND ds_read. Counted vmcnt 2/8/4 (never 0 in steady state).
__global__ __launch_bounds__(512, 2)
void gemm8_kernel(const ushort* __restrict__ Ahi, const ushort* __restrict__ Alo,
                  const ushort* __restrict__ Whi, const ushort* __restrict__ Wlo,
                  const float*  __restrict__ bias, float* __restrict__ C) {
  __shared__ __align__(16) ushort As[2][2][8192];
  __shared__ __align__(16) ushort Bs[2][2][8192];

  const int tid  = threadIdx.x;
  const int lane = tid & 63;
  const int w    = tid >> 6;          // wave 0..7
  const int wm   = w >> 2;            // 0..1
  const int wn   = w & 3;             // 0..3
  const int wofs = w * 512;

  const int swz = (blockIdx.x & 7) * 64 + (blockIdx.x >> 3);
  const int bm  = swz >> 1;           // 0..255
  const int bn  = swz & 1;            // 0..1

  // staging source offsets (inverse-swizzled global, linear LDS dest)
  uint32_t offA0, offA1, offB0, offB1;
  {
    const int d0 = tid * 16;
    const int d1 = 8192 + tid * 16;
    const int s0 = d0 ^ (((d0 >> 9) & 1) << 5);
    const int s1 = d1 ^ (((d1 >> 9) & 1) << 5);
    const int r0 = s0 >> 6, c0 = (s0 & 63) >> 1;
    const int r1 = s1 >> 6, c1 = (s1 & 63) >> 1;
    offA0 = (uint32_t)(bm * 256 + r0) * 512 + c0;
    offA1 = (uint32_t)(bm * 256 + r1) * 512 + c1;
    offB0 = (uint32_t)(bn * 256 + r0) * 512 + c0;
    offB1 = (uint32_t)(bn * 256 + r1) * 512 + c1;
  }

  // fragment ds_read bases (swizzle bit9 is fm/fn-invariant -> imm offsets)
  int abyte = (wm * 128 + (lane & 15)) * 64 + (lane >> 4) * 16;
  abyte ^= ((abyte >> 9) & 1) << 5;
  const int abase = abyte >> 1;
  int bbyte = (wn * 64 + (lane & 15)) * 64 + (lane >> 4) * 16;
  bbyte ^= ((bbyte >> 9) & 1) << 5;
  const int bbase = bbyte >> 1;

  f32x4 acc[8][4] = {};
  bf16x8 af[16];

#define STAGE_A(src, k0v, bsel, kh)                                   \
  GLOAD_LDS16((src) + offA0 + (k0v), &As[bsel][kh][wofs]);            \
  GLOAD_LDS16((src) + offA1 + (k0v), &As[bsel][kh][4096 + wofs]);
#define STAGE_B(src, k0v, bsel, kh)                                   \
  GLOAD_LDS16((src) + offB0 + (k0v), &Bs[bsel][kh][wofs]);            \
  GLOAD_LDS16((src) + offB1 + (k0v), &Bs[bsel][kh][4096 + wofs]);
#define LDA(pb, kh, fm) (*(const bf16x8*)&As[pb][kh][abase + (fm) * 512])
#define LDB(pb, kh, fn) (*(const bf16x8*)&Bs[pb][kh][bbase + (fn) * 512])
#define BF_LOAD(pb, kh)                                               \
  bf0 = LDB(pb, kh, 0); bf1 = LDB(pb, kh, 1);                         \
  bf2 = LDB(pb, kh, 2); bf3 = LDB(pb, kh, 3);
#define AF_LOAD4(pb, kh, ai, f0)                                      \
  af[ai+0] = LDA(pb, kh, f0+0); af[ai+1] = LDA(pb, kh, f0+1);         \
  af[ai+2] = LDA(pb, kh, f0+2); af[ai+3] = LDA(pb, kh, f0+3);
#define MROW(fmi, a)                                                               \
  acc[fmi][0] = __builtin_amdgcn_mfma_f32_16x16x32_bf16(a, bf0, acc[fmi][0],0,0,0);\
  acc[fmi][1] = __builtin_amdgcn_mfma_f32_16x16x32_bf16(a, bf1, acc[fmi][1],0,0,0);\
  acc[fmi][2] = __builtin_amdgcn_mfma_f32_16x16x32_bf16(a, bf2, acc[fmi][2],0,0,0);\
  acc[fmi][3] = __builtin_amdgcn_mfma_f32_16x16x32_bf16(a, bf3, acc[fmi][3],0,0,0);
#define DO_MFMA(ai, fm)                                               \
  __builtin_amdgcn_s_barrier();                                       \
  __builtin_amdgcn_s_setprio(1);                                      \
  MROW(fm+0, af[ai+0]) MROW(fm+1, af[ai+1])                           \
  MROW(fm+2, af[ai+2]) MROW(fm+3, af[ai+3])                           \
  __builtin_amdgcn_s_setprio(0);                                      \
  __builtin_amdgcn_s_barrier();

  // ---- prologue: Ahi(0),Whi(0) both kh + Wlo(0) both kh ----
  STAGE_A(Ahi, 0, 0, 0); STAGE_A(Ahi, 32, 0, 1);
  STAGE_B(Whi, 0, 0, 0); STAGE_B(Whi, 32, 0, 1);
  STAGE_B(Wlo, 0, 1, 0); STAGE_B(Wlo, 32, 1, 1);
  VMCNT(4);
  __builtin_amdgcn_s_barrier();

#pragma unroll 1
  for (int c = 0; c < 8; ++c) {
    const int p0 = c & 1, p1 = p0 ^ 1;
    const int k0 = c * 64;
    const bool more = (c < 7);
    bf16x8 bf0, bf1, bf2, bf3;

    // ---- T0: (c,0) A=Ahi@p0 B=Whi@p0 ----
    BF_LOAD(p0, 0); AF_LOAD4(p0, 0, 0, 0);
    DO_MFMA(0, 0);                                        // ph0
    AF_LOAD4(p0, 0, 4, 4);
    DO_MFMA(4, 4);                                        // ph1
    BF_LOAD(p0, 1); AF_LOAD4(p0, 1, 8, 0);
    STAGE_A(Alo, k0, p0, 0);
    DO_MFMA(8, 0);                                        // ph2
    AF_LOAD4(p0, 1, 12, 4);
    VMCNT(2);
    DO_MFMA(12, 4);                                       // ph3

    // ---- T1: (c,1) B=Wlo@p1, A-frags persist ----
    BF_LOAD(p1, 0);
    STAGE_A(Alo, k0 + 32, p0, 1);
    DO_MFMA(0, 0);                                        // ph0
    if (more) { STAGE_A(Ahi, k0 + 64, p1, 0); }
    DO_MFMA(4, 4);                                        // ph1
    BF_LOAD(p1, 1);
    if (more) { STAGE_A(Ahi, k0 + 96, p1, 1); }
    DO_MFMA(8, 0);                                        // ph2
    if (more) {
      STAGE_B(Whi, k0 + 64, p1, 0); STAGE_B(Whi, k0 + 96, p1, 1);
      VMCNT(8);
    } else { VMCNT(0); }
    DO_MFMA(12, 4);                                       // ph3

    // ---- T2: (c,2) A=Alo@p0, B=Whi@p0 (slot reuse, no B stage) ----
    BF_LOAD(p0, 0); AF_LOAD4(p0, 0, 0, 0);
    DO_MFMA(0, 0);                                        // ph0
    AF_LOAD4(p0, 0, 4, 4);
    if (more) { STAGE_B(Wlo, k0 + 64, p0, 0); }
    DO_MFMA(4, 4);                                        // ph1
    BF_LOAD(p0, 1); AF_LOAD4(p0, 1, 8, 0);
    DO_MFMA(8, 0);                                        // ph2
    AF_LOAD4(p0, 1, 12, 4);
    if (more) { STAGE_B(Wlo, k0 + 96, p0, 1); VMCNT(4); }
    else      { VMCNT(0); }
    DO_MFMA(12, 4);                                       // ph3
  }

  // ---- epilogue: C = acc + bias ; C/D: col=lane&15, row=(lane>>4)*4+j ----
  const int sl = lane >> 4, lr = lane & 15;
  const int cm = bm * 256 + wm * 128;
  const int cnc = bn * 256 + wn * 64;
#pragma unroll
  for (int fn = 0; fn < 4; ++fn) {
    const int col = cnc + fn * 16 + lr;
    const float bv = bias[col];
#pragma unroll
    for (int fm = 0; fm < 8; ++fm) {
      const int rowb = cm + fm * 16 + sl * 4;
#pragma unroll
      for (int j = 0; j < 4; ++j)
        C[(size_t)(rowb + j) * 512 + col] = acc[fm][fn][j] + bv;
    }
  }
#undef STAGE_A
#undef STAGE_B
#undef LDA
#undef LDB
#undef BF_LOAD
#undef AF_LOAD4
#undef MROW
#undef DO_MFMA
}

// ---------- parallel-segment scan ----------
// h_t = relu(l_t + u*h_{t-1}), u>=0: step functions compose as f(h)=max(p,q+s*h).
// T=1024 -> 8 segments of 128. K1: per-(seg,col) triple. K2: prefix-combine + emit.
__global__ __launch_bounds__(256)
void triple_kernel(const float* __restrict__ lin, const float* __restrict__ u,
                   float* __restrict__ P, float* __restrict__ Q, float* __restrict__ S) {
  const int gid = blockIdx.x * 256 + threadIdx.x;   // 0..262143
  const int seg = gid >> 15;
  const int i   = gid & 32767;
  const float uv = u[i & (H_DIM - 1)];
  const float* p = lin + (size_t)(seg * 128) * BH + i;
  float pp = 0.f, qq = 0.f, ss = 1.f;               // identity on h>=0
  float va[8], vb[8];
#pragma unroll
  for (int j = 0; j < 8; ++j) va[j] = p[(size_t)j * BH];
  for (int t0 = 0; t0 < 128; t0 += 16) {
#pragma unroll
    for (int j = 0; j < 8; ++j) vb[j] = p[(size_t)(t0 + 8 + j) * BH];
#pragma unroll
    for (int j = 0; j < 8; ++j) {
      pp = fmaxf(fmaf(uv, pp, va[j]), 0.f);
      qq = fmaf(uv, qq, va[j]);
      ss *= uv;
    }
    if (t0 + 16 < 128) {
#pragma unroll
      for (int j = 0; j < 8; ++j) va[j] = p[(size_t)(t0 + 16 + j) * BH];
    }
#pragma unroll
    for (int j = 0; j < 8; ++j) {
      pp = fmaxf(fmaf(uv, pp, vb[j]), 0.f);
      qq = fmaf(uv, qq, vb[j]);
      ss *= uv;
    }
  }
  P[seg * BH + i] = pp;
  Q[seg * BH + i] = qq;
  S[seg * BH + i] = ss;
}

template <int MODE>
__global__ __launch_bounds__(256)
void apply_kernel(const float* __restrict__ lin, const float* __restrict__ u,
                  const float* __restrict__ P, const float* __restrict__ Q,
                  const float* __restrict__ S,
                  ushort* __restrict__ yhi, ushort* __restrict__ ylo,
                  float* __restrict__ yf, float* __restrict__ hT) {
  const int gid = blockIdx.x * 256 + threadIdx.x;
  const int seg = gid >> 15;
  const int i   = gid & 32767;
  const float uv = u[i & (H_DIM - 1)];
  float hv = 0.f;
  if (uv >= 0.f) {
    for (int j = 0; j < seg; ++j)
      hv = fmaxf(fmaf(S[j * BH + i], hv, Q[j * BH + i]), P[j * BH + i]);
    const int tb = seg * 128;
    const float* p = lin + (size_t)tb * BH + i;
    float va[8], vb[8];
#pragma unroll
    for (int j = 0; j < 8; ++j) va[j] = p[(size_t)j * BH];
    for (int t0 = 0; t0 < 128; t0 += 16) {
#pragma unroll
      for (int j = 0; j < 8; ++j) vb[j] = p[(size_t)(t0 + 8 + j) * BH];
#pragma unroll
      for (int j = 0; j < 8; ++j) {
        hv = fmaxf(fmaf(uv, hv, va[j]), 0.f);
        const size_t o = (size_t)(tb + t0 + j) * BH + i;
        if (MODE == 0) { ushort hb, lb; split1(hv, hb, lb); yhi[o] = hb; ylo[o] = lb; }
        else yf[o] = hv;
      }
      if (t0 + 16 < 128) {
#pragma unroll
        for (int j = 0; j < 8; ++j) va[j] = p[(size_t)(t0 + 16 + j) * BH];
      }
#pragma unroll
      for (int j = 0; j < 8; ++j) {
        hv = fmaxf(fmaf(uv, hv, vb[j]), 0.f);
        const size_t o = (size_t)(tb + t0 + 8 + j) * BH + i;
        if (MODE == 0) { ushort hb, lb; split1(hv, hb, lb); yhi[o] = hb; ylo[o] = lb; }
        else yf[o] = hv;
      }
    }
    if (seg == 7) hT[(i >> 9) * (2 * H_DIM) + (i & (H_DIM - 1))] = hv;
  } else if (seg == 0) {
    // exact sequential fallback for u<0 lanes
    for (int t = 0; t < T_DIM; ++t) {
      const float lv = lin[(size_t)t * BH + i];
      hv = fmaxf(fmaf(uv, hv, lv), 0.f);
      const size_t o = (size_t)t * BH + i;
      if (MODE == 0) { ushort hb, lb; split1(hv, hb, lb); yhi[o] = hb; ylo[o] = lb; }
      else yf[o] = hv;
    }
    hT[(i >> 9) * (2 * H_DIM) + (i & (H_DIM - 1))] = hv;
  }
}

// ---------- launch ----------
extern "C" void kernel_launch(void* const* d_in, const int* in_sizes, int n_in,
                              void* d_out, int out_size, void* d_ws, size_t ws_size,
                              hipStream_t stream) {
  const float* x  = (const float*)d_in[0];
  const float* W0 = (const float*)d_in[1];
  const float* b0 = (const float*)d_in[2];
  const float* u0 = (const float*)d_in[3];
  const float* W1 = (const float*)d_in[4];
  const float* b1 = (const float*)d_in[5];
  const float* u1 = (const float*)d_in[6];
  float* out = (float*)d_out;

  char* ws = (char*)d_ws;
  float*  lin  = (float*)ws;                        // 134 MB
  ushort* phi  = (ushort*)(ws + 134217728ull);      // 67 MB
  ushort* plo  = (ushort*)(ws + 201326592ull);      // 67 MB
  ushort* w0hi = (ushort*)(ws + 268435456ull);
  ushort* w0lo = w0hi + 262144;
  ushort* w1hi = w0lo + 262144;
  ushort* w1lo = w1hi + 262144;

  // layer-0 triples live in d_out (main out region untouched until last kernel);
  // layer-1 triples live in phi region (planes dead after gemm1).
  float* P0 = out;            float* Q0 = out + 262144;  float* S0 = out + 524288;
  float* P1 = (float*)phi;    float* Q1 = P1 + 262144;   float* S1 = P1 + 524288;

  // 1) split inputs to bf16 hi/lo planes
  split4_kernel<<<2048, 256, 0, stream>>>((const float4*)x,  (ushort4*)phi,  (ushort4*)plo,  M_DIM*I_DIM/4);
  split4_kernel<<<256,  256, 0, stream>>>((const float4*)W0, (ushort4*)w0hi, (ushort4*)w0lo, H_DIM*I_DIM/4);
  split4_kernel<<<256,  256, 0, stream>>>((const float4*)W1, (ushort4*)w1hi, (ushort4*)w1lo, H_DIM*H_DIM/4);

  // 2) lin0 = x @ W0^T + b0
  gemm8_kernel<<<512, 512, 0, stream>>>(phi, plo, w0hi, w0lo, b0, lin);

  // 3) scan layer 0 -> ys0 split planes (reuse phi/plo) + hT0
  triple_kernel<<<1024, 256, 0, stream>>>(lin, u0, P0, Q0, S0);
  apply_kernel<0><<<1024, 256, 0, stream>>>(lin, u0, P0, Q0, S0, phi, plo, nullptr, out + OUT_OFF);

  // 4) lin1 = ys0 @ W1^T + b1
  gemm8_kernel<<<512, 512, 0, stream>>>(phi, plo, w1hi, w1lo, b1, lin);

  // 5) scan layer 1 -> out (T,B,H) + hT1
  triple_kernel<<<1024, 256, 0, stream>>>(lin, u1, P1, Q1, S1);
  apply_kernel<1><<<1024, 256, 0, stream>>>(lin, u1, P1, Q1, S1, nullptr, nullptr, out, out + OUT_OFF + H_DIM);
}